// Round 4
// baseline (868.295 us; speedup 1.0000x reference)
//
#include <hip/hip_runtime.h>
#include <hip/hip_bf16.h>

#define NHEADS 3
#define SSH 4
#define NWD 32            // windows per dim
#define PXI 65536         // pixels per image plane
#define SCALE 0.17677669529663687f

// ---------------------------------------------------------------------------
// K0: one-time weight transposes -> WT[c][oc] (288 wide) and WTp[c][oc] (96).
// Enables wave-uniform scalar (s_load) W reads in k1/k5.
// ---------------------------------------------------------------------------
__global__ __launch_bounds__(256) void k0_wt(
    const float* __restrict__ Wqk, const float* __restrict__ Wv,
    const float* __restrict__ Wp, float* __restrict__ WT,
    float* __restrict__ WTp) {
  int i = blockIdx.x * 256 + threadIdx.x;
  if (i < 288 * 96) {
    int c = i % 96, oc = i / 96;
    float w = (oc < 192) ? Wqk[oc * 96 + c] : Wv[(oc - 192) * 96 + c];
    WT[c * 288 + oc] = w;
  }
  if (i < 96 * 96) {
    int c = i % 96, oc = i / 96;
    WTp[c * 96 + oc] = Wp[oc * 96 + c];
  }
}

// ---------------------------------------------------------------------------
// K1: QKV 1x1 conv for image b (GEMM 288x96 @ 96x65536).
// grid (1024 px-tiles, 3 oc-tiles), block 256 (4 waves).
// 64-px tiles: LDS 24KB -> 6 blocks/CU. Wave-uniform s_load W, LDS X.
// ---------------------------------------------------------------------------
__global__ __launch_bounds__(256) void k1_qkv(
    const float* __restrict__ x, const float* __restrict__ WT,
    const float* __restrict__ bqk, const float* __restrict__ bv,
    float* __restrict__ qkv_b, float* __restrict__ v_b, int b) {
  __shared__ __align__(16) float Xt[96 * 64];
  const int tid = threadIdx.x;
  const int pt = blockIdx.x, ot = blockIdx.y;
  const int p0 = pt * 64;

  // stage X tile [96 c][64 px], float4 coalesced
  for (int i = tid; i < 96 * 16; i += 256) {
    int c = i >> 4, f = i & 15;
    *(float4*)&Xt[c * 64 + f * 4] =
        *(const float4*)&x[(size_t)(b * 96 + c) * PXI + p0 + f * 4];
  }
  __syncthreads();

  const int lane = tid & 63;
  const int wvu = __builtin_amdgcn_readfirstlane(tid >> 6);  // wave id 0..3
  const int oc0l = wvu * 24;            // oc offset inside 96-tile
  const int oc0 = ot * 96 + oc0l;       // global oc

  float acc[24];
#pragma unroll
  for (int r = 0; r < 24; r++) acc[r] = 0.f;

  const float* wt = WT + oc0;           // wave-uniform base
#pragma unroll 4
  for (int c = 0; c < 96; c++) {
    float xa = Xt[c * 64 + lane];
    const float* wc = wt + c * 288;     // uniform -> s_load
#pragma unroll
    for (int r = 0; r < 24; r++) acc[r] += wc[r] * xa;
  }

  // bias (scalar)
  float bb[24];
#pragma unroll
  for (int r = 0; r < 24; r++) {
    int oc = oc0 + r;
    bb[r] = (oc < 192) ? bqk[oc] : bv[oc - 192];
  }

  // write windowed qkv (float4 along contiguous oc) + V plane (ot==2)
  {
    int p = p0 + lane;
    int h = p >> 8, w = p & 255;
    int hp = (h + 252) & 255, wp = (w + 252) & 255;  // rolled coords
    int win = (hp >> 3) * NWD + (wp >> 3);
    int n = (hp & 7) * 8 + (wp & 7);
    float* dst = qkv_b + (size_t)(win * 64 + n) * 288 + oc0;
#pragma unroll
    for (int r4 = 0; r4 < 6; r4++) {
      float4 v4;
      v4.x = acc[r4 * 4 + 0] + bb[r4 * 4 + 0];
      v4.y = acc[r4 * 4 + 1] + bb[r4 * 4 + 1];
      v4.z = acc[r4 * 4 + 2] + bb[r4 * 4 + 2];
      v4.w = acc[r4 * 4 + 3] + bb[r4 * 4 + 3];
      *(float4*)&dst[r4 * 4] = v4;
    }
    if (ot == 2) {
#pragma unroll
      for (int r = 0; r < 24; r++)
        v_b[(size_t)(oc0l + r) * PXI + p] = acc[r] + bb[r];
    }
  }
}

// ---------------------------------------------------------------------------
// K2: relative-position bias MLP -> bias_ws[head][n][m]  (fp32)
// ---------------------------------------------------------------------------
__global__ __launch_bounds__(256) void k2_bias(
    const float* __restrict__ Wm1, const float* __restrict__ bm1,
    const float* __restrict__ Wm2, const float* __restrict__ bm2,
    float* __restrict__ bias_ws) {
  int pair = blockIdx.x * 256 + threadIdx.x;  // 0..4095
  int n = pair >> 6, m = pair & 63;
  float d0 = (float)((n >> 3) - (m >> 3));
  float d1 = (float)((n & 7) - (m & 7));
  float r0 = (d0 > 0.f ? 1.f : (d0 < 0.f ? -1.f : 0.f)) * log1pf(fabsf(d0));
  float r1 = (d1 > 0.f ? 1.f : (d1 < 0.f ? -1.f : 0.f)) * log1pf(fabsf(d1));
  float a0 = 0.f, a1 = 0.f, a2 = 0.f;
  for (int j = 0; j < 256; j++) {
    float hb = r0 * Wm1[j] + r1 * Wm1[256 + j] + bm1[j];
    hb = fmaxf(hb, 0.f);
    a0 += hb * Wm2[j * 3 + 0];
    a1 += hb * Wm2[j * 3 + 1];
    a2 += hb * Wm2[j * 3 + 2];
  }
  bias_ws[0 * 4096 + pair] = a0 + bm2[0];
  bias_ws[1 * 4096 + pair] = a1 + bm2[1];
  bias_ws[2 * 4096 + pair] = a2 + bm2[2];
}

// ---------------------------------------------------------------------------
// K3: windowed attention, one WAVE per (window, head), lane = output row n.
// grid (1024 windows, 3 heads), block 64.
// Q row + full score row S[64] live in VGPRs -> softmax is in-lane (no
// shuffles, no LDS for Q/P). Only K (then V, same buffer) staged in LDS
// [64][36] = 9.2 KB; rows read via uniform-address broadcast ds_read_b128.
// Normalization folded into O. 16 blocks/CU = 4 waves/SIMD.
// ---------------------------------------------------------------------------
__global__ __launch_bounds__(64, 4) void k3_attn(
    const float* __restrict__ qkv_b, const float* __restrict__ bias_ws,
    float* __restrict__ o_b) {
  __shared__ __align__(16) float KV[64 * 36];
  const int lane = threadIdx.x;
  const int win = blockIdx.x;
  const int hd = blockIdx.y;
  const int wh = win >> 5, ww = win & 31;
  const int row8 = lane >> 3, c4 = (lane & 7) * 4;

  // ---- issue global loads: Q row (this lane's pixel n = lane), K tile
  const float* qrow = qkv_b + (size_t)(win * 64 + lane) * 288 + hd * 32;
  float4 q4[8];
#pragma unroll
  for (int t = 0; t < 8; t++) q4[t] = *(const float4*)&qrow[4 * t];

  const float* kbase = qkv_b + (size_t)win * 64 * 288 + 96 + hd * 32;
  float4 k4[8];
#pragma unroll
  for (int t = 0; t < 8; t++)
    k4[t] = *(const float4*)&kbase[(size_t)(t * 8 + row8) * 288 + c4];

  // K -> LDS (stride 36, coalesced-written, conflict-light)
#pragma unroll
  for (int t = 0; t < 8; t++)
    *(float4*)&KV[(t * 8 + row8) * 36 + c4] = k4[t];

  // Q scaled into scalar regs
  float q[32];
#pragma unroll
  for (int t = 0; t < 8; t++) {
    q[4 * t + 0] = q4[t].x * SCALE;
    q[4 * t + 1] = q4[t].y * SCALE;
    q[4 * t + 2] = q4[t].z * SCALE;
    q[4 * t + 3] = q4[t].w * SCALE;
  }

  // ---- bias row straight into the score accumulators
  const float* bw = bias_ws + hd * 4096 + lane * 64;
  float s[64];
#pragma unroll
  for (int t = 0; t < 16; t++) {
    float4 b4 = *(const float4*)&bw[4 * t];
    s[4 * t + 0] = b4.x; s[4 * t + 1] = b4.y;
    s[4 * t + 2] = b4.z; s[4 * t + 3] = b4.w;
  }

  // ---- shift-mask for edge windows (block-uniform branch; 63/1024 blocks)
  if (wh == 31 || ww == 31) {
    int rn = ((wh == 31) ? ((row8 < 4) ? 1 : 2) : 0) * 3 +
             ((ww == 31) ? (((lane & 7) < 4) ? 1 : 2) : 0);
#pragma unroll
    for (int m = 0; m < 64; m++) {
      int rm = ((wh == 31) ? (((m >> 3) < 4) ? 1 : 2) : 0) * 3 +
               ((ww == 31) ? (((m & 7) < 4) ? 1 : 2) : 0);
      if (rm != rn) s[m] -= 100.f;
    }
  }

  // ---- QK^T: lane n computes its whole row; K rows broadcast from LDS
#pragma unroll
  for (int m = 0; m < 64; m++) {
    float sum = s[m];
#pragma unroll
    for (int t = 0; t < 8; t++) {
      float4 kk = *(const float4*)&KV[m * 36 + 4 * t];
      sum += q[4 * t + 0] * kk.x + q[4 * t + 1] * kk.y +
             q[4 * t + 2] * kk.z + q[4 * t + 3] * kk.w;
    }
    s[m] = sum;
  }

  // ---- issue V global loads; latency hides under softmax
  float4 vr[8];
#pragma unroll
  for (int t = 0; t < 8; t++)
    vr[t] = *(const float4*)&kbase[(size_t)(t * 8 + row8) * 288 + 96 + c4];

  // ---- softmax fully in-lane (tree max / tree sum), defer normalization
  float tr[32];
#pragma unroll
  for (int i = 0; i < 32; i++) tr[i] = fmaxf(s[i], s[i + 32]);
#pragma unroll
  for (int i = 0; i < 16; i++) tr[i] = fmaxf(tr[i], tr[i + 16]);
#pragma unroll
  for (int i = 0; i < 8; i++) tr[i] = fmaxf(tr[i], tr[i + 8]);
#pragma unroll
  for (int i = 0; i < 4; i++) tr[i] = fmaxf(tr[i], tr[i + 4]);
  float mx = fmaxf(fmaxf(tr[0], tr[1]), fmaxf(tr[2], tr[3]));
#pragma unroll
  for (int m = 0; m < 64; m++) s[m] = __expf(s[m] - mx);
#pragma unroll
  for (int i = 0; i < 32; i++) tr[i] = s[i] + s[i + 32];
#pragma unroll
  for (int i = 0; i < 16; i++) tr[i] = tr[i] + tr[i + 16];
#pragma unroll
  for (int i = 0; i < 8; i++) tr[i] = tr[i] + tr[i + 8];
#pragma unroll
  for (int i = 0; i < 4; i++) tr[i] = tr[i] + tr[i + 4];
  float inv = 1.f / ((tr[0] + tr[1]) + (tr[2] + tr[3]));

  // ---- V overwrites K region (wave-internal in-order DS; QK reads done)
#pragma unroll
  for (int t = 0; t < 8; t++)
    *(float4*)&KV[(t * 8 + row8) * 36 + c4] = vr[t];

  // ---- PV: O[n][d] = sum_m P[n][m] * V[m][d], V rows broadcast from LDS
  float o[32];
#pragma unroll
  for (int d = 0; d < 32; d++) o[d] = 0.f;
#pragma unroll
  for (int m = 0; m < 64; m++) {
    float p = s[m];
#pragma unroll
    for (int t = 0; t < 8; t++) {
      float4 vv = *(const float4*)&KV[m * 36 + 4 * t];
      o[4 * t + 0] += p * vv.x;
      o[4 * t + 1] += p * vv.y;
      o[4 * t + 2] += p * vv.z;
      o[4 * t + 3] += p * vv.w;
    }
  }

  // ---- store (normalize here): pixel of row n, 32 channels of this head
  const int hpix = ((wh << 3) + row8 + SSH) & 255;
  const int wpix = ((ww << 3) + (lane & 7) + SSH) & 255;
  float* ob = o_b + (size_t)hd * 32 * PXI + (hpix << 8) + wpix;
#pragma unroll
  for (int c = 0; c < 32; c++)
    ob[(size_t)c * PXI] = o[c] * inv;
}

// ---------------------------------------------------------------------------
// K4: depthwise 5x5 (reflect pad) + bdw + O -> t_b, per image. grid 24576.
// ---------------------------------------------------------------------------
__global__ __launch_bounds__(256) void k4_dw(
    const float* __restrict__ v_b, const float* __restrict__ o_b,
    const float* __restrict__ Wdw, const float* __restrict__ bdw,
    float* __restrict__ t_b) {
  const int blk = blockIdx.x;      // 0..24575
  const int c = blk >> 8;
  const int h = blk & 255;
  const int w = threadIdx.x;
  __shared__ float wd[25];
  __shared__ float bd;
  if (threadIdx.x < 25) wd[threadIdx.x] = Wdw[c * 25 + threadIdx.x];
  if (threadIdx.x == 32) bd = bdw[c];
  __syncthreads();

  const float* vp = v_b + ((size_t)c << 16);
  float acc = bd;
#pragma unroll
  for (int dy = 0; dy < 5; dy++) {
    int hh = h + dy - 2;
    hh = hh < 0 ? -hh : (hh > 255 ? 510 - hh : hh);
    const float* row = vp + (hh << 8);
#pragma unroll
    for (int dx = 0; dx < 5; dx++) {
      int wx = w + dx - 2;
      wx = wx < 0 ? -wx : (wx > 255 ? 510 - wx : wx);
      acc += row[wx] * wd[dy * 5 + dx];
    }
  }
  size_t idx = ((size_t)c << 16) + (h << 8) + w;
  acc += o_b[idx];
  t_b[idx] = acc;
}

// ---------------------------------------------------------------------------
// K5: projection GEMM 96x96 for image b -> d_out (fp32 NCHW).
// Same scheme as k1: 64-px tiles, 24KB LDS, 6 blocks/CU. grid 1024.
// ---------------------------------------------------------------------------
__global__ __launch_bounds__(256) void k5_proj(
    const float* __restrict__ t_b, const float* __restrict__ WTp,
    const float* __restrict__ bp, float* __restrict__ out, int b) {
  __shared__ __align__(16) float Xt[96 * 64];
  const int tid = threadIdx.x;
  const int pt = blockIdx.x;
  const int p0 = pt * 64;

  for (int i = tid; i < 96 * 16; i += 256) {
    int c = i >> 4, f = i & 15;
    *(float4*)&Xt[c * 64 + f * 4] =
        *(const float4*)&t_b[(size_t)c * PXI + p0 + f * 4];
  }
  __syncthreads();

  const int lane = tid & 63;
  const int wvu = __builtin_amdgcn_readfirstlane(tid >> 6);
  const int oc0 = wvu * 24;

  float acc[24];
#pragma unroll
  for (int r = 0; r < 24; r++) acc[r] = 0.f;

  const float* wt = WTp + oc0;
#pragma unroll 4
  for (int c = 0; c < 96; c++) {
    float xa = Xt[c * 64 + lane];
    const float* wc = wt + c * 96;      // uniform -> s_load
#pragma unroll
    for (int r = 0; r < 24; r++) acc[r] += wc[r] * xa;
  }

  int p = p0 + lane;
#pragma unroll
  for (int r = 0; r < 24; r++) {
    int oc = oc0 + r;
    out[(size_t)(b * 96 + oc) * PXI + p] = acc[r] + bp[oc];
  }
}

// ---------------------------------------------------------------------------
extern "C" void kernel_launch(void* const* d_in, const int* in_sizes, int n_in,
                              void* d_out, int out_size, void* d_ws,
                              size_t ws_size, hipStream_t stream) {
  const float* x   = (const float*)d_in[0];
  const float* Wv  = (const float*)d_in[1];
  const float* bv  = (const float*)d_in[2];
  const float* Wqk = (const float*)d_in[3];
  const float* bqk = (const float*)d_in[4];
  const float* Wm1 = (const float*)d_in[5];
  const float* bm1 = (const float*)d_in[6];
  const float* Wm2 = (const float*)d_in[7];
  const float* bm2 = (const float*)d_in[8];
  const float* Wdw = (const float*)d_in[9];
  const float* bdw = (const float*)d_in[10];
  const float* Wp  = (const float*)d_in[11];
  const float* bp  = (const float*)d_in[12];

  // per-image fp32 workspace (reused across b):
  //   [0, 75497472)            qkv_b  fp32 [1024][64][288] (t_b aliases)
  //   [75497472, 100663296)    v_b    fp32 [96][65536]
  //   [100663296, 125829120)   o_b    fp32 [96][65536]
  //   [125829120, 125878272)   bias_ws fp32 [3][64][64]
  //   [125878272, 125988864)   WT  fp32 [96][288]
  //   [125988864, 126025728)   WTp fp32 [96][96]
  char* ws = (char*)d_ws;
  float* qkv_b = (float*)ws;
  float* t_b   = (float*)ws;
  float* v_b   = (float*)(ws + 75497472);
  float* o_b   = (float*)(ws + 100663296);
  float* bias_ws = (float*)(ws + 125829120);
  float* WT    = (float*)(ws + 125878272);
  float* WTp   = (float*)(ws + 125988864);

  k0_wt<<<108, 256, 0, stream>>>(Wqk, Wv, Wp, WT, WTp);
  k2_bias<<<16, 256, 0, stream>>>(Wm1, bm1, Wm2, bm2, bias_ws);
  for (int b = 0; b < 4; b++) {
    k1_qkv<<<dim3(1024, 3), 256, 0, stream>>>(x, WT, bqk, bv, qkv_b, v_b, b);
    k3_attn<<<dim3(1024, 3), 64, 0, stream>>>(qkv_b, bias_ws, o_b);
    k4_dw<<<24576, 256, 0, stream>>>(v_b, o_b, Wdw, bdw, t_b);
    k5_proj<<<1024, 256, 0, stream>>>(t_b, WTp, bp, (float*)d_out, b);
  }
}

// Round 5
// 777.448 us; speedup vs baseline: 1.1169x; 1.1169x over previous
//
#include <hip/hip_runtime.h>
#include <hip/hip_bf16.h>
#include <hip/hip_fp16.h>

#define NHEADS 3
#define SSH 4
#define NWD 32            // windows per dim
#define PXI 65536         // pixels per image plane
#define SCALE 0.17677669529663687f

// ---------------------------------------------------------------------------
// K0: one-time weight transposes -> WT[c][oc] (288 wide) and WTp[c][oc] (96).
// Enables wave-uniform scalar (s_load) W reads in k1/k5.
// ---------------------------------------------------------------------------
__global__ __launch_bounds__(256) void k0_wt(
    const float* __restrict__ Wqk, const float* __restrict__ Wv,
    const float* __restrict__ Wp, float* __restrict__ WT,
    float* __restrict__ WTp) {
  int i = blockIdx.x * 256 + threadIdx.x;
  if (i < 288 * 96) {
    int c = i % 96, oc = i / 96;
    float w = (oc < 192) ? Wqk[oc * 96 + c] : Wv[(oc - 192) * 96 + c];
    WT[c * 288 + oc] = w;
  }
  if (i < 96 * 96) {
    int c = i % 96, oc = i / 96;
    WTp[c * 96 + oc] = Wp[oc * 96 + c];
  }
}

// ---------------------------------------------------------------------------
// K1: QKV 1x1 conv for image b (GEMM 288x96 @ 96x65536).
// grid (1024 px-tiles, 3 oc-tiles), block 256 (4 waves).
// Wave-uniform s_load W, LDS X (24KB -> 6 blocks/CU).
// qkv stored FP16 windowed [win][n][288h]: each lane's 24-oc chunk = 48 B
// contiguous -> zero write amplification (was 3x with fp32 16B chunks).
// V additionally stored fp32 in NCHW plane for the depthwise conv.
// ---------------------------------------------------------------------------
__global__ __launch_bounds__(256) void k1_qkv(
    const float* __restrict__ x, const float* __restrict__ WT,
    const float* __restrict__ bqk, const float* __restrict__ bv,
    __half* __restrict__ qkv_h, float* __restrict__ v_b, int b) {
  __shared__ __align__(16) float Xt[96 * 64];
  const int tid = threadIdx.x;
  const int pt = blockIdx.x, ot = blockIdx.y;
  const int p0 = pt * 64;

  // stage X tile [96 c][64 px], float4 coalesced
  for (int i = tid; i < 96 * 16; i += 256) {
    int c = i >> 4, f = i & 15;
    *(float4*)&Xt[c * 64 + f * 4] =
        *(const float4*)&x[(size_t)(b * 96 + c) * PXI + p0 + f * 4];
  }
  __syncthreads();

  const int lane = tid & 63;
  const int wvu = __builtin_amdgcn_readfirstlane(tid >> 6);  // wave id 0..3
  const int oc0l = wvu * 24;            // oc offset inside 96-tile
  const int oc0 = ot * 96 + oc0l;       // global oc

  float acc[24];
#pragma unroll
  for (int r = 0; r < 24; r++) acc[r] = 0.f;

  const float* wt = WT + oc0;           // wave-uniform base
#pragma unroll 4
  for (int c = 0; c < 96; c++) {
    float xa = Xt[c * 64 + lane];
    const float* wc = wt + c * 288;     // uniform -> s_load
#pragma unroll
    for (int r = 0; r < 24; r++) acc[r] += wc[r] * xa;
  }

  // bias (scalar)
#pragma unroll
  for (int r = 0; r < 24; r++) {
    int oc = oc0 + r;
    acc[r] += (oc < 192) ? bqk[oc] : bv[oc - 192];
  }

  // write windowed qkv fp16 (48 B contiguous per lane) + V plane (ot==2)
  {
    int p = p0 + lane;
    int h = p >> 8, w = p & 255;
    int hp = (h + 252) & 255, wp = (w + 252) & 255;  // rolled coords
    int win = (hp >> 3) * NWD + (wp >> 3);
    int n = (hp & 7) * 8 + (wp & 7);

    __align__(16) __half2 hv[12];
#pragma unroll
    for (int r = 0; r < 12; r++)
      hv[r] = __floats2half2_rn(acc[2 * r], acc[2 * r + 1]);
    __half* dst = qkv_h + (size_t)(win * 64 + n) * 288 + oc0;
    const float4* hv4 = (const float4*)hv;
    *(float4*)&dst[0]  = hv4[0];
    *(float4*)&dst[8]  = hv4[1];
    *(float4*)&dst[16] = hv4[2];

    if (ot == 2) {
#pragma unroll
      for (int r = 0; r < 24; r++)
        v_b[(size_t)(oc0l + r) * PXI + p] = acc[r];
    }
  }
}

// ---------------------------------------------------------------------------
// K2: relative-position bias MLP -> bias_ws[head][n][m]  (fp32)
// ---------------------------------------------------------------------------
__global__ __launch_bounds__(256) void k2_bias(
    const float* __restrict__ Wm1, const float* __restrict__ bm1,
    const float* __restrict__ Wm2, const float* __restrict__ bm2,
    float* __restrict__ bias_ws) {
  int pair = blockIdx.x * 256 + threadIdx.x;  // 0..4095
  int n = pair >> 6, m = pair & 63;
  float d0 = (float)((n >> 3) - (m >> 3));
  float d1 = (float)((n & 7) - (m & 7));
  float r0 = (d0 > 0.f ? 1.f : (d0 < 0.f ? -1.f : 0.f)) * log1pf(fabsf(d0));
  float r1 = (d1 > 0.f ? 1.f : (d1 < 0.f ? -1.f : 0.f)) * log1pf(fabsf(d1));
  float a0 = 0.f, a1 = 0.f, a2 = 0.f;
  for (int j = 0; j < 256; j++) {
    float hb = r0 * Wm1[j] + r1 * Wm1[256 + j] + bm1[j];
    hb = fmaxf(hb, 0.f);
    a0 += hb * Wm2[j * 3 + 0];
    a1 += hb * Wm2[j * 3 + 1];
    a2 += hb * Wm2[j * 3 + 2];
  }
  bias_ws[0 * 4096 + pair] = a0 + bm2[0];
  bias_ws[1 * 4096 + pair] = a1 + bm2[1];
  bias_ws[2 * 4096 + pair] = a2 + bm2[2];
}

// ---------------------------------------------------------------------------
// K3: windowed attention, one WAVE per (window, head), lane = output row n.
// grid (1024 windows, 3 heads), block 64. fp16 qkv loads, fp32 compute.
// Q row + score row S[64] in VGPRs; softmax in-lane; K (then V, same
// buffer) staged fp32 in LDS [64][36] = 9.2 KB.
// ---------------------------------------------------------------------------
__global__ __launch_bounds__(64, 4) void k3_attn(
    const __half* __restrict__ qkv_h, const float* __restrict__ bias_ws,
    float* __restrict__ o_b) {
  __shared__ __align__(16) float KV[64 * 36];
  const int lane = threadIdx.x;
  const int win = blockIdx.x;
  const int hd = blockIdx.y;
  const int wh = win >> 5, ww = win & 31;
  const int row8 = lane >> 3, c4 = (lane & 7) * 4;

  // ---- issue global loads: Q row (this lane's pixel n = lane), K tile
  const __half* qrow = qkv_h + (size_t)(win * 64 + lane) * 288 + hd * 32;
  float4 qraw[4];
  const float4* qp = (const float4*)qrow;   // 16B-aligned (576|entry, 64|hd)
#pragma unroll
  for (int t = 0; t < 4; t++) qraw[t] = qp[t];

  const __half* kbase = qkv_h + (size_t)win * 64 * 288 + 96 + hd * 32;
  float2 kraw[8];
#pragma unroll
  for (int t = 0; t < 8; t++)
    kraw[t] = *(const float2*)&kbase[(size_t)(t * 8 + row8) * 288 + c4];

  // K -> LDS fp32 (stride 36)
#pragma unroll
  for (int t = 0; t < 8; t++) {
    const __half2* hh = (const __half2*)&kraw[t];
    float2 a = __half22float2(hh[0]), b2 = __half22float2(hh[1]);
    *(float4*)&KV[(t * 8 + row8) * 36 + c4] = make_float4(a.x, a.y, b2.x, b2.y);
  }

  // Q scaled into scalar regs
  float q[32];
#pragma unroll
  for (int t = 0; t < 4; t++) {
    const __half2* hh = (const __half2*)&qraw[t];
#pragma unroll
    for (int u = 0; u < 4; u++) {
      float2 f = __half22float2(hh[u]);
      q[8 * t + 2 * u + 0] = f.x * SCALE;
      q[8 * t + 2 * u + 1] = f.y * SCALE;
    }
  }

  // ---- bias row straight into the score accumulators
  const float* bw = bias_ws + hd * 4096 + lane * 64;
  float s[64];
#pragma unroll
  for (int t = 0; t < 16; t++) {
    float4 b4 = *(const float4*)&bw[4 * t];
    s[4 * t + 0] = b4.x; s[4 * t + 1] = b4.y;
    s[4 * t + 2] = b4.z; s[4 * t + 3] = b4.w;
  }

  // ---- shift-mask for edge windows (block-uniform branch; 63/1024 blocks)
  if (wh == 31 || ww == 31) {
    int rn = ((wh == 31) ? ((row8 < 4) ? 1 : 2) : 0) * 3 +
             ((ww == 31) ? (((lane & 7) < 4) ? 1 : 2) : 0);
#pragma unroll
    for (int m = 0; m < 64; m++) {
      int rm = ((wh == 31) ? (((m >> 3) < 4) ? 1 : 2) : 0) * 3 +
               ((ww == 31) ? (((m & 7) < 4) ? 1 : 2) : 0);
      if (rm != rn) s[m] -= 100.f;
    }
  }

  // ---- QK^T: lane n computes its whole row; K rows broadcast from LDS
#pragma unroll
  for (int m = 0; m < 64; m++) {
    float sum = s[m];
#pragma unroll
    for (int t = 0; t < 8; t++) {
      float4 kk = *(const float4*)&KV[m * 36 + 4 * t];
      sum += q[4 * t + 0] * kk.x + q[4 * t + 1] * kk.y +
             q[4 * t + 2] * kk.z + q[4 * t + 3] * kk.w;
    }
    s[m] = sum;
  }

  // ---- issue V global loads; latency hides under softmax
  float2 vraw[8];
#pragma unroll
  for (int t = 0; t < 8; t++)
    vraw[t] = *(const float2*)&kbase[(size_t)(t * 8 + row8) * 288 + 96 + c4];

  // ---- softmax fully in-lane (tree max / tree sum), defer normalization
  float tr[32];
#pragma unroll
  for (int i = 0; i < 32; i++) tr[i] = fmaxf(s[i], s[i + 32]);
#pragma unroll
  for (int i = 0; i < 16; i++) tr[i] = fmaxf(tr[i], tr[i + 16]);
#pragma unroll
  for (int i = 0; i < 8; i++) tr[i] = fmaxf(tr[i], tr[i + 8]);
#pragma unroll
  for (int i = 0; i < 4; i++) tr[i] = fmaxf(tr[i], tr[i + 4]);
  float mx = fmaxf(fmaxf(tr[0], tr[1]), fmaxf(tr[2], tr[3]));
#pragma unroll
  for (int m = 0; m < 64; m++) s[m] = __expf(s[m] - mx);
#pragma unroll
  for (int i = 0; i < 32; i++) tr[i] = s[i] + s[i + 32];
#pragma unroll
  for (int i = 0; i < 16; i++) tr[i] = tr[i] + tr[i + 16];
#pragma unroll
  for (int i = 0; i < 8; i++) tr[i] = tr[i] + tr[i + 8];
#pragma unroll
  for (int i = 0; i < 4; i++) tr[i] = tr[i] + tr[i + 4];
  float inv = 1.f / ((tr[0] + tr[1]) + (tr[2] + tr[3]));

  // ---- V overwrites K region (wave-internal in-order DS; QK reads done)
#pragma unroll
  for (int t = 0; t < 8; t++) {
    const __half2* hh = (const __half2*)&vraw[t];
    float2 a = __half22float2(hh[0]), b2 = __half22float2(hh[1]);
    *(float4*)&KV[(t * 8 + row8) * 36 + c4] = make_float4(a.x, a.y, b2.x, b2.y);
  }

  // ---- PV: O[n][d] = sum_m P[n][m] * V[m][d], V rows broadcast from LDS
  float o[32];
#pragma unroll
  for (int d = 0; d < 32; d++) o[d] = 0.f;
#pragma unroll
  for (int m = 0; m < 64; m++) {
    float p = s[m];
#pragma unroll
    for (int t = 0; t < 8; t++) {
      float4 vv = *(const float4*)&KV[m * 36 + 4 * t];
      o[4 * t + 0] += p * vv.x;
      o[4 * t + 1] += p * vv.y;
      o[4 * t + 2] += p * vv.z;
      o[4 * t + 3] += p * vv.w;
    }
  }

  // ---- store (normalize here): pixel of row n, 32 channels of this head
  const int hpix = ((wh << 3) + row8 + SSH) & 255;
  const int wpix = ((ww << 3) + (lane & 7) + SSH) & 255;
  float* ob = o_b + (size_t)hd * 32 * PXI + (hpix << 8) + wpix;
#pragma unroll
  for (int c = 0; c < 32; c++)
    ob[(size_t)c * PXI] = o[c] * inv;
}

// ---------------------------------------------------------------------------
// K4: depthwise 5x5 (reflect pad) + bdw + O -> t_b, per image. grid 24576.
// ---------------------------------------------------------------------------
__global__ __launch_bounds__(256) void k4_dw(
    const float* __restrict__ v_b, const float* __restrict__ o_b,
    const float* __restrict__ Wdw, const float* __restrict__ bdw,
    float* __restrict__ t_b) {
  const int blk = blockIdx.x;      // 0..24575
  const int c = blk >> 8;
  const int h = blk & 255;
  const int w = threadIdx.x;
  __shared__ float wd[25];
  __shared__ float bd;
  if (threadIdx.x < 25) wd[threadIdx.x] = Wdw[c * 25 + threadIdx.x];
  if (threadIdx.x == 32) bd = bdw[c];
  __syncthreads();

  const float* vp = v_b + ((size_t)c << 16);
  float acc = bd;
#pragma unroll
  for (int dy = 0; dy < 5; dy++) {
    int hh = h + dy - 2;
    hh = hh < 0 ? -hh : (hh > 255 ? 510 - hh : hh);
    const float* row = vp + (hh << 8);
#pragma unroll
    for (int dx = 0; dx < 5; dx++) {
      int wx = w + dx - 2;
      wx = wx < 0 ? -wx : (wx > 255 ? 510 - wx : wx);
      acc += row[wx] * wd[dy * 5 + dx];
    }
  }
  size_t idx = ((size_t)c << 16) + (h << 8) + w;
  acc += o_b[idx];
  t_b[idx] = acc;
}

// ---------------------------------------------------------------------------
// K5: projection GEMM 96x96 for image b -> d_out (fp32 NCHW).
// Same scheme as k1: 64-px tiles, 24KB LDS, 6 blocks/CU. grid 1024.
// ---------------------------------------------------------------------------
__global__ __launch_bounds__(256) void k5_proj(
    const float* __restrict__ t_b, const float* __restrict__ WTp,
    const float* __restrict__ bp, float* __restrict__ out, int b) {
  __shared__ __align__(16) float Xt[96 * 64];
  const int tid = threadIdx.x;
  const int pt = blockIdx.x;
  const int p0 = pt * 64;

  for (int i = tid; i < 96 * 16; i += 256) {
    int c = i >> 4, f = i & 15;
    *(float4*)&Xt[c * 64 + f * 4] =
        *(const float4*)&t_b[(size_t)c * PXI + p0 + f * 4];
  }
  __syncthreads();

  const int lane = tid & 63;
  const int wvu = __builtin_amdgcn_readfirstlane(tid >> 6);
  const int oc0 = wvu * 24;

  float acc[24];
#pragma unroll
  for (int r = 0; r < 24; r++) acc[r] = 0.f;

  const float* wt = WTp + oc0;
#pragma unroll 4
  for (int c = 0; c < 96; c++) {
    float xa = Xt[c * 64 + lane];
    const float* wc = wt + c * 96;      // uniform -> s_load
#pragma unroll
    for (int r = 0; r < 24; r++) acc[r] += wc[r] * xa;
  }

  int p = p0 + lane;
#pragma unroll
  for (int r = 0; r < 24; r++) {
    int oc = oc0 + r;
    out[(size_t)(b * 96 + oc) * PXI + p] = acc[r] + bp[oc];
  }
}

// ---------------------------------------------------------------------------
extern "C" void kernel_launch(void* const* d_in, const int* in_sizes, int n_in,
                              void* d_out, int out_size, void* d_ws,
                              size_t ws_size, hipStream_t stream) {
  const float* x   = (const float*)d_in[0];
  const float* Wv  = (const float*)d_in[1];
  const float* bv  = (const float*)d_in[2];
  const float* Wqk = (const float*)d_in[3];
  const float* bqk = (const float*)d_in[4];
  const float* Wm1 = (const float*)d_in[5];
  const float* bm1 = (const float*)d_in[6];
  const float* Wm2 = (const float*)d_in[7];
  const float* bm2 = (const float*)d_in[8];
  const float* Wdw = (const float*)d_in[9];
  const float* bdw = (const float*)d_in[10];
  const float* Wp  = (const float*)d_in[11];
  const float* bp  = (const float*)d_in[12];

  // per-image workspace (reused across b):
  //   [0, 37748736)            qkv_h  fp16 [1024][64][288]  (t_b aliases)
  //   [37748736, 62914560)     v_b    fp32 [96][65536]
  //   [62914560, 88080384)     o_b    fp32 [96][65536]
  //   [88080384, 88129536)     bias_ws fp32 [3][64][64]
  //   [88129536, 88240128)     WT  fp32 [96][288]
  //   [88240128, 88276992)     WTp fp32 [96][96]
  char* ws = (char*)d_ws;
  __half* qkv_h = (__half*)ws;
  float* t_b   = (float*)ws;           // 25 MB, alias of dead qkv region
  float* v_b   = (float*)(ws + 37748736);
  float* o_b   = (float*)(ws + 62914560);
  float* bias_ws = (float*)(ws + 88080384);
  float* WT    = (float*)(ws + 88129536);
  float* WTp   = (float*)(ws + 88240128);

  k0_wt<<<108, 256, 0, stream>>>(Wqk, Wv, Wp, WT, WTp);
  k2_bias<<<16, 256, 0, stream>>>(Wm1, bm1, Wm2, bm2, bias_ws);
  for (int b = 0; b < 4; b++) {
    k1_qkv<<<dim3(1024, 3), 256, 0, stream>>>(x, WT, bqk, bv, qkv_h, v_b, b);
    k3_attn<<<dim3(1024, 3), 64, 0, stream>>>(qkv_h, bias_ws, o_b);
    k4_dw<<<24576, 256, 0, stream>>>(v_b, o_b, Wdw, bdw, t_b);
    k5_proj<<<1024, 256, 0, stream>>>(t_b, WTp, bp, (float*)d_out, b);
  }
}

// Round 6
// 767.745 us; speedup vs baseline: 1.1310x; 1.0126x over previous
//
#include <hip/hip_runtime.h>
#include <hip/hip_bf16.h>
#include <hip/hip_fp16.h>

#define NHEADS 3
#define SSH 4
#define NWD 32            // windows per dim
#define PXI 65536         // pixels per image plane
#define SCALE 0.17677669529663687f

typedef _Float16 hf2 __attribute__((ext_vector_type(2)));

#if __has_builtin(__builtin_amdgcn_fdot2)
#define FDOT2(a, b, c) __builtin_amdgcn_fdot2((a), (b), (c), false)
#else
#define FDOT2(a, b, c) ((float)(a)[0] * (float)(b)[0] + (float)(a)[1] * (float)(b)[1] + (c))
#endif

// ---------------------------------------------------------------------------
// K0: one-time weight transposes -> WT[c][oc] (288 wide) and WTp[c][oc] (96).
// Enables wave-uniform scalar (s_load) W reads in k1/k5.
// ---------------------------------------------------------------------------
__global__ __launch_bounds__(256) void k0_wt(
    const float* __restrict__ Wqk, const float* __restrict__ Wv,
    const float* __restrict__ Wp, float* __restrict__ WT,
    float* __restrict__ WTp) {
  int i = blockIdx.x * 256 + threadIdx.x;
  if (i < 288 * 96) {
    int c = i % 96, oc = i / 96;
    float w = (oc < 192) ? Wqk[oc * 96 + c] : Wv[(oc - 192) * 96 + c];
    WT[c * 288 + oc] = w;
  }
  if (i < 96 * 96) {
    int c = i % 96, oc = i / 96;
    WTp[c * 96 + oc] = Wp[oc * 96 + c];
  }
}

// ---------------------------------------------------------------------------
// K1: QKV 1x1 conv for image b (GEMM 288x96 @ 96x65536).
// grid (1024 px-tiles, 3 oc-tiles), block 256 (4 waves).
// Wave-uniform s_load W, LDS X (24KB -> 6 blocks/CU).
// qkv stored FP16 windowed [win][n][288h]; V also fp32 NCHW plane.
// ---------------------------------------------------------------------------
__global__ __launch_bounds__(256) void k1_qkv(
    const float* __restrict__ x, const float* __restrict__ WT,
    const float* __restrict__ bqk, const float* __restrict__ bv,
    __half* __restrict__ qkv_h, float* __restrict__ v_b, int b) {
  __shared__ __align__(16) float Xt[96 * 64];
  const int tid = threadIdx.x;
  const int pt = blockIdx.x, ot = blockIdx.y;
  const int p0 = pt * 64;

  // stage X tile [96 c][64 px], float4 coalesced
  for (int i = tid; i < 96 * 16; i += 256) {
    int c = i >> 4, f = i & 15;
    *(float4*)&Xt[c * 64 + f * 4] =
        *(const float4*)&x[(size_t)(b * 96 + c) * PXI + p0 + f * 4];
  }
  __syncthreads();

  const int lane = tid & 63;
  const int wvu = __builtin_amdgcn_readfirstlane(tid >> 6);  // wave id 0..3
  const int oc0l = wvu * 24;            // oc offset inside 96-tile
  const int oc0 = ot * 96 + oc0l;       // global oc

  float acc[24];
#pragma unroll
  for (int r = 0; r < 24; r++) acc[r] = 0.f;

  const float* wt = WT + oc0;           // wave-uniform base
#pragma unroll 4
  for (int c = 0; c < 96; c++) {
    float xa = Xt[c * 64 + lane];
    const float* wc = wt + c * 288;     // uniform -> s_load
#pragma unroll
    for (int r = 0; r < 24; r++) acc[r] += wc[r] * xa;
  }

  // bias (scalar)
#pragma unroll
  for (int r = 0; r < 24; r++) {
    int oc = oc0 + r;
    acc[r] += (oc < 192) ? bqk[oc] : bv[oc - 192];
  }

  // write windowed qkv fp16 (48 B contiguous per lane) + V plane (ot==2)
  {
    int p = p0 + lane;
    int h = p >> 8, w = p & 255;
    int hp = (h + 252) & 255, wp = (w + 252) & 255;  // rolled coords
    int win = (hp >> 3) * NWD + (wp >> 3);
    int n = (hp & 7) * 8 + (wp & 7);

    __align__(16) __half2 hv[12];
#pragma unroll
    for (int r = 0; r < 12; r++)
      hv[r] = __floats2half2_rn(acc[2 * r], acc[2 * r + 1]);
    __half* dst = qkv_h + (size_t)(win * 64 + n) * 288 + oc0;
    const float4* hv4 = (const float4*)hv;
    *(float4*)&dst[0]  = hv4[0];
    *(float4*)&dst[8]  = hv4[1];
    *(float4*)&dst[16] = hv4[2];

    if (ot == 2) {
#pragma unroll
      for (int r = 0; r < 24; r++)
        v_b[(size_t)(oc0l + r) * PXI + p] = acc[r];
    }
  }
}

// ---------------------------------------------------------------------------
// K2: relative-position bias MLP -> bias_ws[head][n][m]  (fp32)
// ---------------------------------------------------------------------------
__global__ __launch_bounds__(256) void k2_bias(
    const float* __restrict__ Wm1, const float* __restrict__ bm1,
    const float* __restrict__ Wm2, const float* __restrict__ bm2,
    float* __restrict__ bias_ws) {
  int pair = blockIdx.x * 256 + threadIdx.x;  // 0..4095
  int n = pair >> 6, m = pair & 63;
  float d0 = (float)((n >> 3) - (m >> 3));
  float d1 = (float)((n & 7) - (m & 7));
  float r0 = (d0 > 0.f ? 1.f : (d0 < 0.f ? -1.f : 0.f)) * log1pf(fabsf(d0));
  float r1 = (d1 > 0.f ? 1.f : (d1 < 0.f ? -1.f : 0.f)) * log1pf(fabsf(d1));
  float a0 = 0.f, a1 = 0.f, a2 = 0.f;
  for (int j = 0; j < 256; j++) {
    float hb = r0 * Wm1[j] + r1 * Wm1[256 + j] + bm1[j];
    hb = fmaxf(hb, 0.f);
    a0 += hb * Wm2[j * 3 + 0];
    a1 += hb * Wm2[j * 3 + 1];
    a2 += hb * Wm2[j * 3 + 2];
  }
  bias_ws[0 * 4096 + pair] = a0 + bm2[0];
  bias_ws[1 * 4096 + pair] = a1 + bm2[1];
  bias_ws[2 * 4096 + pair] = a2 + bm2[2];
}

// ---------------------------------------------------------------------------
// K3: windowed attention. Block = 128 threads (2 waves) per (window, head).
// Thread (n = tid>>1, half = tid&1): row n, m-range [32*half, 32*half+32).
// Pair lanes combine softmax stats (1 shfl each) and O (32 shfl).
// K staged fp16 in LDS [64][40h] (5.1KB), QK via v_dot2_f32_f16 (fp32 acc).
// V staged fp32 in LDS [64][36] (9.2KB). One __syncthreads total.
// 14.3KB LDS; ~4 waves/SIMD -> ~16 waves/CU (was ~6.4).
// ---------------------------------------------------------------------------
__global__ __launch_bounds__(128, 4) void k3_attn(
    const __half* __restrict__ qkv_h, const float* __restrict__ bias_ws,
    float* __restrict__ o_b) {
  __shared__ __align__(16) __half Kh[64 * 40];
  __shared__ __align__(16) float Vs[64 * 36];
  const int tid = threadIdx.x;
  const int n = tid >> 1;        // output row 0..63
  const int half = tid & 1;      // m-half
  const int win = blockIdx.x;
  const int hd = blockIdx.y;
  const int wh = win >> 5, ww = win & 31;

  const __half* base = qkv_h + (size_t)win * 64 * 288 + hd * 32;

  // ---- stage K fp16 -> LDS: 256 chunks of 8 halves (16B)
#pragma unroll
  for (int i = 0; i < 2; i++) {
    int idx = tid + 128 * i;             // 0..255
    int row = idx >> 2, qd = idx & 3;
    float4 kk = *(const float4*)(base + 96 + (size_t)row * 288 + qd * 8);
    *(float4*)&Kh[row * 40 + qd * 8] = kk;
  }
  // ---- stage V fp16 -> fp32 LDS: 512 chunks of 4 floats
#pragma unroll
  for (int i = 0; i < 4; i++) {
    int idx = tid + 128 * i;             // 0..511
    int row = idx >> 3, qd = idx & 7;
    float2 vv = *(const float2*)(base + 192 + (size_t)row * 288 + qd * 4);
    const __half2* hh = (const __half2*)&vv;
    float2 a = __half22float2(hh[0]), b2 = __half22float2(hh[1]);
    *(float4*)&Vs[row * 36 + qd * 4] = make_float4(a.x, a.y, b2.x, b2.y);
  }

  // ---- Q row n into hf2 regs (fp16 pairs for fdot2)
  hf2 q2[16];
  {
    const float4* qp = (const float4*)(base + (size_t)n * 288);
#pragma unroll
    for (int t = 0; t < 4; t++) {
      float4 f = qp[t];
      const hf2* h = (const hf2*)&f;
      q2[4 * t + 0] = h[0]; q2[4 * t + 1] = h[1];
      q2[4 * t + 2] = h[2]; q2[4 * t + 3] = h[3];
    }
  }

  // ---- bias for own half-row
  float s[32];
  {
    const float* bw = bias_ws + hd * 4096 + n * 64 + half * 32;
#pragma unroll
    for (int t = 0; t < 8; t++) {
      float4 b4 = *(const float4*)&bw[4 * t];
      s[4 * t + 0] = b4.x; s[4 * t + 1] = b4.y;
      s[4 * t + 2] = b4.z; s[4 * t + 3] = b4.w;
    }
  }

  // ---- shift-mask (block-uniform branch; 63/1024 windows)
  if (wh == 31 || ww == 31) {
    int rn = ((wh == 31) ? (((n >> 3) < 4) ? 1 : 2) : 0) * 3 +
             ((ww == 31) ? (((n & 7) < 4) ? 1 : 2) : 0);
#pragma unroll
    for (int j = 0; j < 32; j++) {
      int m = half * 32 + j;
      int rm = ((wh == 31) ? (((m >> 3) < 4) ? 1 : 2) : 0) * 3 +
               ((ww == 31) ? (((m & 7) < 4) ? 1 : 2) : 0);
      if (rm != rn) s[j] -= 100.f;
    }
  }

  __syncthreads();

  // ---- QK^T: 32 columns (own half), K rows broadcast from fp16 LDS
#pragma unroll
  for (int j = 0; j < 32; j++) {
    int m = half * 32 + j;
    float d0 = 0.f, d1 = 0.f;
#pragma unroll
    for (int u = 0; u < 2; u++) {
      float4 kk = *(const float4*)&Kh[m * 40 + 8 * u];
      const hf2* kh = (const hf2*)&kk;
      d0 = FDOT2(q2[4 * u + 0], kh[0], d0);
      d0 = FDOT2(q2[4 * u + 1], kh[1], d0);
      d0 = FDOT2(q2[4 * u + 2], kh[2], d0);
      d0 = FDOT2(q2[4 * u + 3], kh[3], d0);
    }
#pragma unroll
    for (int u = 2; u < 4; u++) {
      float4 kk = *(const float4*)&Kh[m * 40 + 8 * u];
      const hf2* kh = (const hf2*)&kk;
      d1 = FDOT2(q2[4 * u + 0], kh[0], d1);
      d1 = FDOT2(q2[4 * u + 1], kh[1], d1);
      d1 = FDOT2(q2[4 * u + 2], kh[2], d1);
      d1 = FDOT2(q2[4 * u + 3], kh[3], d1);
    }
    s[j] += SCALE * (d0 + d1);
  }

  // ---- softmax: own 32 + pair combine (1 shfl for max, 1 for sum)
  float tr[16];
#pragma unroll
  for (int i = 0; i < 16; i++) tr[i] = fmaxf(s[i], s[i + 16]);
#pragma unroll
  for (int i = 0; i < 8; i++) tr[i] = fmaxf(tr[i], tr[i + 8]);
#pragma unroll
  for (int i = 0; i < 4; i++) tr[i] = fmaxf(tr[i], tr[i + 4]);
  float mx = fmaxf(fmaxf(tr[0], tr[1]), fmaxf(tr[2], tr[3]));
  mx = fmaxf(mx, __shfl_xor(mx, 1));
#pragma unroll
  for (int j = 0; j < 32; j++) s[j] = __expf(s[j] - mx);
#pragma unroll
  for (int i = 0; i < 16; i++) tr[i] = s[i] + s[i + 16];
#pragma unroll
  for (int i = 0; i < 8; i++) tr[i] = tr[i] + tr[i + 8];
#pragma unroll
  for (int i = 0; i < 4; i++) tr[i] = tr[i] + tr[i + 4];
  float sm = (tr[0] + tr[1]) + (tr[2] + tr[3]);
  sm += __shfl_xor(sm, 1);
  float inv = 1.f / sm;

  // ---- PV over own m-half: O[n][0..32) partial
  float o[32];
#pragma unroll
  for (int d = 0; d < 32; d++) o[d] = 0.f;
#pragma unroll 4
  for (int j = 0; j < 32; j++) {
    int m = half * 32 + j;
    float p = s[j];
#pragma unroll
    for (int u = 0; u < 8; u++) {
      float4 vv = *(const float4*)&Vs[m * 36 + 4 * u];
      o[4 * u + 0] += p * vv.x;
      o[4 * u + 1] += p * vv.y;
      o[4 * u + 2] += p * vv.z;
      o[4 * u + 3] += p * vv.w;
    }
  }
  // pair combine
#pragma unroll
  for (int d = 0; d < 32; d++) o[d] += __shfl_xor(o[d], 1);

  // ---- store 16 channels per thread (static branch on half: no dyn index)
  const int hpix = ((wh << 3) + (n >> 3) + SSH) & 255;
  const int wpix = ((ww << 3) + (n & 7) + SSH) & 255;
  float* ob = o_b + (size_t)(hd * 32 + half * 16) * PXI + (hpix << 8) + wpix;
  if (half == 0) {
#pragma unroll
    for (int c = 0; c < 16; c++) ob[(size_t)c * PXI] = o[c] * inv;
  } else {
#pragma unroll
    for (int c = 0; c < 16; c++) ob[(size_t)c * PXI] = o[c + 16] * inv;
  }
}

// ---------------------------------------------------------------------------
// K4: depthwise 5x5 (reflect pad) + bdw + O -> t_b, per image. grid 24576.
// ---------------------------------------------------------------------------
__global__ __launch_bounds__(256) void k4_dw(
    const float* __restrict__ v_b, const float* __restrict__ o_b,
    const float* __restrict__ Wdw, const float* __restrict__ bdw,
    float* __restrict__ t_b) {
  const int blk = blockIdx.x;      // 0..24575
  const int c = blk >> 8;
  const int h = blk & 255;
  const int w = threadIdx.x;
  __shared__ float wd[25];
  __shared__ float bd;
  if (threadIdx.x < 25) wd[threadIdx.x] = Wdw[c * 25 + threadIdx.x];
  if (threadIdx.x == 32) bd = bdw[c];
  __syncthreads();

  const float* vp = v_b + ((size_t)c << 16);
  float acc = bd;
#pragma unroll
  for (int dy = 0; dy < 5; dy++) {
    int hh = h + dy - 2;
    hh = hh < 0 ? -hh : (hh > 255 ? 510 - hh : hh);
    const float* row = vp + (hh << 8);
#pragma unroll
    for (int dx = 0; dx < 5; dx++) {
      int wx = w + dx - 2;
      wx = wx < 0 ? -wx : (wx > 255 ? 510 - wx : wx);
      acc += row[wx] * wd[dy * 5 + dx];
    }
  }
  size_t idx = ((size_t)c << 16) + (h << 8) + w;
  acc += o_b[idx];
  t_b[idx] = acc;
}

// ---------------------------------------------------------------------------
// K5: projection GEMM 96x96 for image b -> d_out (fp32 NCHW).
// Same scheme as k1: 64-px tiles, 24KB LDS, 6 blocks/CU. grid 1024.
// ---------------------------------------------------------------------------
__global__ __launch_bounds__(256) void k5_proj(
    const float* __restrict__ t_b, const float* __restrict__ WTp,
    const float* __restrict__ bp, float* __restrict__ out, int b) {
  __shared__ __align__(16) float Xt[96 * 64];
  const int tid = threadIdx.x;
  const int pt = blockIdx.x;
  const int p0 = pt * 64;

  for (int i = tid; i < 96 * 16; i += 256) {
    int c = i >> 4, f = i & 15;
    *(float4*)&Xt[c * 64 + f * 4] =
        *(const float4*)&t_b[(size_t)c * PXI + p0 + f * 4];
  }
  __syncthreads();

  const int lane = tid & 63;
  const int wvu = __builtin_amdgcn_readfirstlane(tid >> 6);
  const int oc0 = wvu * 24;

  float acc[24];
#pragma unroll
  for (int r = 0; r < 24; r++) acc[r] = 0.f;

  const float* wt = WTp + oc0;
#pragma unroll 4
  for (int c = 0; c < 96; c++) {
    float xa = Xt[c * 64 + lane];
    const float* wc = wt + c * 96;      // uniform -> s_load
#pragma unroll
    for (int r = 0; r < 24; r++) acc[r] += wc[r] * xa;
  }

  int p = p0 + lane;
#pragma unroll
  for (int r = 0; r < 24; r++) {
    int oc = oc0 + r;
    out[(size_t)(b * 96 + oc) * PXI + p] = acc[r] + bp[oc];
  }
}

// ---------------------------------------------------------------------------
extern "C" void kernel_launch(void* const* d_in, const int* in_sizes, int n_in,
                              void* d_out, int out_size, void* d_ws,
                              size_t ws_size, hipStream_t stream) {
  const float* x   = (const float*)d_in[0];
  const float* Wv  = (const float*)d_in[1];
  const float* bv  = (const float*)d_in[2];
  const float* Wqk = (const float*)d_in[3];
  const float* bqk = (const float*)d_in[4];
  const float* Wm1 = (const float*)d_in[5];
  const float* bm1 = (const float*)d_in[6];
  const float* Wm2 = (const float*)d_in[7];
  const float* bm2 = (const float*)d_in[8];
  const float* Wdw = (const float*)d_in[9];
  const float* bdw = (const float*)d_in[10];
  const float* Wp  = (const float*)d_in[11];
  const float* bp  = (const float*)d_in[12];

  // per-image workspace (reused across b):
  //   [0, 37748736)            qkv_h  fp16 [1024][64][288]  (t_b aliases)
  //   [37748736, 62914560)     v_b    fp32 [96][65536]
  //   [62914560, 88080384)     o_b    fp32 [96][65536]
  //   [88080384, 88129536)     bias_ws fp32 [3][64][64]
  //   [88129536, 88240128)     WT  fp32 [96][288]
  //   [88240128, 88276992)     WTp fp32 [96][96]
  char* ws = (char*)d_ws;
  __half* qkv_h = (__half*)ws;
  float* t_b   = (float*)ws;           // 25 MB, alias of dead qkv region
  float* v_b   = (float*)(ws + 37748736);
  float* o_b   = (float*)(ws + 62914560);
  float* bias_ws = (float*)(ws + 88080384);
  float* WT    = (float*)(ws + 88129536);
  float* WTp   = (float*)(ws + 88240128);

  k0_wt<<<108, 256, 0, stream>>>(Wqk, Wv, Wp, WT, WTp);
  k2_bias<<<16, 256, 0, stream>>>(Wm1, bm1, Wm2, bm2, bias_ws);
  for (int b = 0; b < 4; b++) {
    k1_qkv<<<dim3(1024, 3), 256, 0, stream>>>(x, WT, bqk, bv, qkv_h, v_b, b);
    k3_attn<<<dim3(1024, 3), 128, 0, stream>>>(qkv_h, bias_ws, o_b);
    k4_dw<<<24576, 256, 0, stream>>>(v_b, o_b, Wdw, bdw, t_b);
    k5_proj<<<1024, 256, 0, stream>>>(t_b, WTp, bp, (float*)d_out, b);
  }
}

// Round 7
// 712.466 us; speedup vs baseline: 1.2187x; 1.0776x over previous
//
#include <hip/hip_runtime.h>
#include <hip/hip_bf16.h>
#include <hip/hip_fp16.h>

#define NHEADS 3
#define SSH 4
#define NWD 32            // windows per dim
#define PXI 65536         // pixels per image plane
#define SCALE 0.17677669529663687f

typedef _Float16 f16x8 __attribute__((ext_vector_type(8)));
typedef float f32x4 __attribute__((ext_vector_type(4)));

// ---------------------------------------------------------------------------
// K0: one-time weight transposes -> WT[c][oc] (288 wide) and WTp[c][oc] (96).
// Enables wave-uniform scalar (s_load) W reads in k1/k5.
// ---------------------------------------------------------------------------
__global__ __launch_bounds__(256) void k0_wt(
    const float* __restrict__ Wqk, const float* __restrict__ Wv,
    const float* __restrict__ Wp, float* __restrict__ WT,
    float* __restrict__ WTp) {
  int i = blockIdx.x * 256 + threadIdx.x;
  if (i < 288 * 96) {
    int c = i % 96, oc = i / 96;
    float w = (oc < 192) ? Wqk[oc * 96 + c] : Wv[(oc - 192) * 96 + c];
    WT[c * 288 + oc] = w;
  }
  if (i < 96 * 96) {
    int c = i % 96, oc = i / 96;
    WTp[c * 96 + oc] = Wp[oc * 96 + c];
  }
}

// ---------------------------------------------------------------------------
// K1: QKV 1x1 conv for image b (GEMM 288x96 @ 96x65536).
// grid (1024 px-tiles, 3 oc-tiles), block 256 (4 waves).
// Wave-uniform s_load W, LDS X (24KB -> 6 blocks/CU).
// qkv stored FP16 windowed [win][n][288h]; V also fp32 NCHW plane.
// ---------------------------------------------------------------------------
__global__ __launch_bounds__(256) void k1_qkv(
    const float* __restrict__ x, const float* __restrict__ WT,
    const float* __restrict__ bqk, const float* __restrict__ bv,
    __half* __restrict__ qkv_h, float* __restrict__ v_b, int b) {
  __shared__ __align__(16) float Xt[96 * 64];
  const int tid = threadIdx.x;
  const int pt = blockIdx.x, ot = blockIdx.y;
  const int p0 = pt * 64;

  // stage X tile [96 c][64 px], float4 coalesced
  for (int i = tid; i < 96 * 16; i += 256) {
    int c = i >> 4, f = i & 15;
    *(float4*)&Xt[c * 64 + f * 4] =
        *(const float4*)&x[(size_t)(b * 96 + c) * PXI + p0 + f * 4];
  }
  __syncthreads();

  const int lane = tid & 63;
  const int wvu = __builtin_amdgcn_readfirstlane(tid >> 6);  // wave id 0..3
  const int oc0l = wvu * 24;            // oc offset inside 96-tile
  const int oc0 = ot * 96 + oc0l;       // global oc

  float acc[24];
#pragma unroll
  for (int r = 0; r < 24; r++) acc[r] = 0.f;

  const float* wt = WT + oc0;           // wave-uniform base
#pragma unroll 4
  for (int c = 0; c < 96; c++) {
    float xa = Xt[c * 64 + lane];
    const float* wc = wt + c * 288;     // uniform -> s_load
#pragma unroll
    for (int r = 0; r < 24; r++) acc[r] += wc[r] * xa;
  }

  // bias (scalar)
#pragma unroll
  for (int r = 0; r < 24; r++) {
    int oc = oc0 + r;
    acc[r] += (oc < 192) ? bqk[oc] : bv[oc - 192];
  }

  // write windowed qkv fp16 (48 B contiguous per lane) + V plane (ot==2)
  {
    int p = p0 + lane;
    int h = p >> 8, w = p & 255;
    int hp = (h + 252) & 255, wp = (w + 252) & 255;  // rolled coords
    int win = (hp >> 3) * NWD + (wp >> 3);
    int n = (hp & 7) * 8 + (wp & 7);

    __align__(16) __half2 hv[12];
#pragma unroll
    for (int r = 0; r < 12; r++)
      hv[r] = __floats2half2_rn(acc[2 * r], acc[2 * r + 1]);
    __half* dst = qkv_h + (size_t)(win * 64 + n) * 288 + oc0;
    const float4* hv4 = (const float4*)hv;
    *(float4*)&dst[0]  = hv4[0];
    *(float4*)&dst[8]  = hv4[1];
    *(float4*)&dst[16] = hv4[2];

    if (ot == 2) {
#pragma unroll
      for (int r = 0; r < 24; r++)
        v_b[(size_t)(oc0l + r) * PXI + p] = acc[r];
    }
  }
}

// ---------------------------------------------------------------------------
// K2: relative-position bias MLP -> bias_c in MFMA C-fragment layout:
// bias_c[((hd*64 + lane)*64) + (ti*4+tj)*4 + reg], where for S[n][m]:
// ti=n>>4, g=(n>>2)&3, reg=n&3, tj=m>>4, c=m&15, lane=(g<<4)|c.
// k3 then loads its 16 accumulator float4s as one 256B contiguous run.
// ---------------------------------------------------------------------------
__global__ __launch_bounds__(256) void k2_bias(
    const float* __restrict__ Wm1, const float* __restrict__ bm1,
    const float* __restrict__ Wm2, const float* __restrict__ bm2,
    float* __restrict__ bias_c) {
  int pair = blockIdx.x * 256 + threadIdx.x;  // 0..4095
  int n = pair >> 6, m = pair & 63;
  float d0 = (float)((n >> 3) - (m >> 3));
  float d1 = (float)((n & 7) - (m & 7));
  float r0 = (d0 > 0.f ? 1.f : (d0 < 0.f ? -1.f : 0.f)) * log1pf(fabsf(d0));
  float r1 = (d1 > 0.f ? 1.f : (d1 < 0.f ? -1.f : 0.f)) * log1pf(fabsf(d1));
  float a0 = 0.f, a1 = 0.f, a2 = 0.f;
  for (int j = 0; j < 256; j++) {
    float hb = r0 * Wm1[j] + r1 * Wm1[256 + j] + bm1[j];
    hb = fmaxf(hb, 0.f);
    a0 += hb * Wm2[j * 3 + 0];
    a1 += hb * Wm2[j * 3 + 1];
    a2 += hb * Wm2[j * 3 + 2];
  }
  int ti = n >> 4, g = (n >> 2) & 3, reg = n & 3;
  int tj = m >> 4, c = m & 15;
  int lane = (g << 4) | c;
  int idx = lane * 64 + (ti * 4 + tj) * 4 + reg;
  bias_c[0 * 4096 + idx] = a0 + bm2[0];
  bias_c[1 * 4096 + idx] = a1 + bm2[1];
  bias_c[2 * 4096 + idx] = a2 + bm2[2];
}

// ---------------------------------------------------------------------------
// K3: windowed attention via MFMA. One wave per (window, head).
// grid (1024, 3), block 64. fp16 operands, fp32 accumulate.
// QK^T: S[64][64] = Q.K^T as 4x4 tiles of mfma_f32_16x16x32_f16
//   (Q/K frags loaded straight from global; bias preloaded as C).
// Softmax: S range is provably < e^5 -> skip max-subtract; sum via
//   4 in-lane adds + 4 shfl_xor per row; normalization deferred to store.
// PV: P staged fp16 in LDS [64][72h] with col^8 XOR swizzle for rows>=8;
//   V frags gathered from global (2B loads, L2-hot). 16 more MFMA.
// No barriers (single wave). LDS 9.2KB.
// ---------------------------------------------------------------------------
__global__ __launch_bounds__(64) void k3_attn(
    const __half* __restrict__ qkv_h, const float* __restrict__ bias_c,
    float* __restrict__ o_b) {
  __shared__ _Float16 P_lds[64 * 72];   // 9216 B
  const int lane = threadIdx.x;
  const int g = lane >> 4;             // frag k-block / C row-group
  const int c = lane & 15;             // frag row/col within tile
  const int win = blockIdx.x;
  const int hd = blockIdx.y;
  const int wh = win >> 5, ww = win & 31;

  const __half* qb = qkv_h + (size_t)win * 64 * 288 + hd * 32;

  // ---- load Q/K fragments directly from global (L2-hot)
  // A-frag (Q): row n = 16*tn + c, k = 8*g + i  (16B contiguous)
  // B-frag (K): col m = 16*tm + c, k = 8*g + i
  f16x8 qf[4], kf[4];
#pragma unroll
  for (int t = 0; t < 4; t++) {
    qf[t] = *(const f16x8*)(const void*)&qb[(size_t)(16 * t + c) * 288 + 8 * g];
    kf[t] = *(const f16x8*)(const void*)&qb[(size_t)(16 * t + c) * 288 + 96 + 8 * g];
  }
  // fold softmax scale into Q (fp16 mul, pk ops)
#pragma unroll
  for (int t = 0; t < 4; t++)
#pragma unroll
    for (int e = 0; e < 8; e++) qf[t][e] *= (_Float16)SCALE;

  // ---- bias preload in C layout: 16 float4 = 256B contiguous per lane
  f32x4 S[4][4];
  {
    const float* bc = bias_c + (size_t)hd * 4096 + lane * 64;
#pragma unroll
    for (int ti = 0; ti < 4; ti++)
#pragma unroll
      for (int tj = 0; tj < 4; tj++)
        S[ti][tj] = *(const f32x4*)&bc[(ti * 4 + tj) * 4];
  }

  // ---- shift-mask (uniform branch; 63/1024 windows)
  if (wh == 31 || ww == 31) {
#pragma unroll
    for (int ti = 0; ti < 4; ti++)
#pragma unroll
      for (int r = 0; r < 4; r++) {
        int row = 16 * ti + 4 * g + r;
        int rn = ((wh == 31) ? (((row >> 3) < 4) ? 1 : 2) : 0) * 3 +
                 ((ww == 31) ? (((row & 7) < 4) ? 1 : 2) : 0);
#pragma unroll
        for (int tj = 0; tj < 4; tj++) {
          int m = 16 * tj + c;
          int rm = ((wh == 31) ? (((m >> 3) < 4) ? 1 : 2) : 0) * 3 +
                   ((ww == 31) ? (((m & 7) < 4) ? 1 : 2) : 0);
          if (rm != rn) S[ti][tj][r] -= 100.f;
        }
      }
  }

  // ---- QK^T: 16 MFMA, C = bias(+mask)
#pragma unroll
  for (int tn = 0; tn < 4; tn++)
#pragma unroll
    for (int tm = 0; tm < 4; tm++)
      S[tn][tm] = __builtin_amdgcn_mfma_f32_16x16x32_f16(qf[tn], kf[tm],
                                                         S[tn][tm], 0, 0, 0);

  // ---- issue V gathers now (latency hides under softmax)
  // B-frag (V): col d = 16*td + c, k m = 32*km + 8*g + i
  const __half* vbse = qb + 192;
  f16x8 vf[2][2];
#pragma unroll
  for (int td = 0; td < 2; td++)
#pragma unroll
    for (int km = 0; km < 2; km++) {
      f16x8 v = {};
#pragma unroll
      for (int i = 0; i < 8; i++)
        v[i] = *(const _Float16*)&vbse[(size_t)(32 * km + 8 * g + i) * 288 +
                                       16 * td + c];
      vf[td][km] = v;
    }

  // ---- softmax (no max-subtract: S bounded by ~5; masked entries ~ -100)
#pragma unroll
  for (int ti = 0; ti < 4; ti++)
#pragma unroll
    for (int tj = 0; tj < 4; tj++)
#pragma unroll
      for (int r = 0; r < 4; r++) S[ti][tj][r] = __expf(S[ti][tj][r]);

  float invs[4][4];
#pragma unroll
  for (int ti = 0; ti < 4; ti++)
#pragma unroll
    for (int r = 0; r < 4; r++) {
      float sm = (S[ti][0][r] + S[ti][1][r]) + (S[ti][2][r] + S[ti][3][r]);
      sm += __shfl_xor(sm, 1);
      sm += __shfl_xor(sm, 2);
      sm += __shfl_xor(sm, 4);
      sm += __shfl_xor(sm, 8);
      invs[ti][r] = 1.f / sm;
    }

  // ---- P -> fp16 LDS [row][72h], col XOR 8 when row&8 (bank de-alias)
  {
    const int cx = (4 * g) & 8;        // row&8 is uniform per lane (g>=2)
#pragma unroll
    for (int ti = 0; ti < 4; ti++)
#pragma unroll
      for (int r = 0; r < 4; r++) {
        int row = 16 * ti + 4 * g + r;
        int rx = (4 * g + r) & 8;      // == row&8
#pragma unroll
        for (int tj = 0; tj < 4; tj++)
          P_lds[row * 72 + ((16 * tj + c) ^ rx)] = (_Float16)S[ti][tj][r];
      }
    (void)cx;
  }

  // ---- PV: O[64][32] = P.V as 4x2 tiles, K=64 (2 chained MFMA)
  // A-frag (P): row n = 16*tn + c, k m = 32*km + 8*g + i
  f32x4 O[4][2];
#pragma unroll
  for (int tn = 0; tn < 4; tn++) {
    const int row = 16 * tn + c;
    const int rx = c & 8;
    f16x8 pf0 = *(const f16x8*)(const void*)&P_lds[row * 72 + ((8 * g) ^ rx)];
    f16x8 pf1 = *(const f16x8*)(const void*)&P_lds[row * 72 + ((32 + 8 * g) ^ rx)];
#pragma unroll
    for (int td = 0; td < 2; td++) {
      f32x4 oo = {0.f, 0.f, 0.f, 0.f};
      oo = __builtin_amdgcn_mfma_f32_16x16x32_f16(pf0, vf[td][0], oo, 0, 0, 0);
      oo = __builtin_amdgcn_mfma_f32_16x16x32_f16(pf1, vf[td][1], oo, 0, 0, 0);
      O[tn][td] = oo;
    }
  }

  // ---- store (normalize by row sum here)
#pragma unroll
  for (int tn = 0; tn < 4; tn++)
#pragma unroll
    for (int r = 0; r < 4; r++) {
      int row = 16 * tn + 4 * g + r;
      int hpix = ((wh << 3) + (row >> 3) + SSH) & 255;
      int wpix = ((ww << 3) + (row & 7) + SSH) & 255;
      size_t pix = (size_t)(hpix << 8) + wpix;
      float inv = invs[tn][r];
#pragma unroll
      for (int td = 0; td < 2; td++) {
        int cch = hd * 32 + 16 * td + c;
        o_b[(size_t)cch * PXI + pix] = O[tn][td][r] * inv;
      }
    }
}

// ---------------------------------------------------------------------------
// K4: depthwise 5x5 (reflect pad) + bdw + O -> t_b, per image. grid 24576.
// ---------------------------------------------------------------------------
__global__ __launch_bounds__(256) void k4_dw(
    const float* __restrict__ v_b, const float* __restrict__ o_b,
    const float* __restrict__ Wdw, const float* __restrict__ bdw,
    float* __restrict__ t_b) {
  const int blk = blockIdx.x;      // 0..24575
  const int c = blk >> 8;
  const int h = blk & 255;
  const int w = threadIdx.x;
  __shared__ float wd[25];
  __shared__ float bd;
  if (threadIdx.x < 25) wd[threadIdx.x] = Wdw[c * 25 + threadIdx.x];
  if (threadIdx.x == 32) bd = bdw[c];
  __syncthreads();

  const float* vp = v_b + ((size_t)c << 16);
  float acc = bd;
#pragma unroll
  for (int dy = 0; dy < 5; dy++) {
    int hh = h + dy - 2;
    hh = hh < 0 ? -hh : (hh > 255 ? 510 - hh : hh);
    const float* row = vp + (hh << 8);
#pragma unroll
    for (int dx = 0; dx < 5; dx++) {
      int wx = w + dx - 2;
      wx = wx < 0 ? -wx : (wx > 255 ? 510 - wx : wx);
      acc += row[wx] * wd[dy * 5 + dx];
    }
  }
  size_t idx = ((size_t)c << 16) + (h << 8) + w;
  acc += o_b[idx];
  t_b[idx] = acc;
}

// ---------------------------------------------------------------------------
// K5: projection GEMM 96x96 for image b -> d_out (fp32 NCHW).
// Same scheme as k1: 64-px tiles, 24KB LDS, 6 blocks/CU. grid 1024.
// ---------------------------------------------------------------------------
__global__ __launch_bounds__(256) void k5_proj(
    const float* __restrict__ t_b, const float* __restrict__ WTp,
    const float* __restrict__ bp, float* __restrict__ out, int b) {
  __shared__ __align__(16) float Xt[96 * 64];
  const int tid = threadIdx.x;
  const int pt = blockIdx.x;
  const int p0 = pt * 64;

  for (int i = tid; i < 96 * 16; i += 256) {
    int c = i >> 4, f = i & 15;
    *(float4*)&Xt[c * 64 + f * 4] =
        *(const float4*)&t_b[(size_t)c * PXI + p0 + f * 4];
  }
  __syncthreads();

  const int lane = tid & 63;
  const int wvu = __builtin_amdgcn_readfirstlane(tid >> 6);
  const int oc0 = wvu * 24;

  float acc[24];
#pragma unroll
  for (int r = 0; r < 24; r++) acc[r] = 0.f;

  const float* wt = WTp + oc0;
#pragma unroll 4
  for (int c = 0; c < 96; c++) {
    float xa = Xt[c * 64 + lane];
    const float* wc = wt + c * 96;      // uniform -> s_load
#pragma unroll
    for (int r = 0; r < 24; r++) acc[r] += wc[r] * xa;
  }

  int p = p0 + lane;
#pragma unroll
  for (int r = 0; r < 24; r++) {
    int oc = oc0 + r;
    out[(size_t)(b * 96 + oc) * PXI + p] = acc[r] + bp[oc];
  }
}

// ---------------------------------------------------------------------------
extern "C" void kernel_launch(void* const* d_in, const int* in_sizes, int n_in,
                              void* d_out, int out_size, void* d_ws,
                              size_t ws_size, hipStream_t stream) {
  const float* x   = (const float*)d_in[0];
  const float* Wv  = (const float*)d_in[1];
  const float* bv  = (const float*)d_in[2];
  const float* Wqk = (const float*)d_in[3];
  const float* bqk = (const float*)d_in[4];
  const float* Wm1 = (const float*)d_in[5];
  const float* bm1 = (const float*)d_in[6];
  const float* Wm2 = (const float*)d_in[7];
  const float* bm2 = (const float*)d_in[8];
  const float* Wdw = (const float*)d_in[9];
  const float* bdw = (const float*)d_in[10];
  const float* Wp  = (const float*)d_in[11];
  const float* bp  = (const float*)d_in[12];

  // per-image workspace (reused across b):
  //   [0, 37748736)            qkv_h  fp16 [1024][64][288]  (t_b aliases)
  //   [37748736, 62914560)     v_b    fp32 [96][65536]
  //   [62914560, 88080384)     o_b    fp32 [96][65536]
  //   [88080384, 88129536)     bias_c fp32 [3][64][64] (C-frag layout)
  //   [88129536, 88240128)     WT  fp32 [96][288]
  //   [88240128, 88276992)     WTp fp32 [96][96]
  char* ws = (char*)d_ws;
  __half* qkv_h = (__half*)ws;
  float* t_b   = (float*)ws;           // 25 MB, alias of dead qkv region
  float* v_b   = (float*)(ws + 37748736);
  float* o_b   = (float*)(ws + 62914560);
  float* bias_c = (float*)(ws + 88080384);
  float* WT    = (float*)(ws + 88129536);
  float* WTp   = (float*)(ws + 88240128);

  k0_wt<<<108, 256, 0, stream>>>(Wqk, Wv, Wp, WT, WTp);
  k2_bias<<<16, 256, 0, stream>>>(Wm1, bm1, Wm2, bm2, bias_c);
  for (int b = 0; b < 4; b++) {
    k1_qkv<<<dim3(1024, 3), 256, 0, stream>>>(x, WT, bqk, bv, qkv_h, v_b, b);
    k3_attn<<<dim3(1024, 3), 64, 0, stream>>>(qkv_h, bias_c, o_b);
    k4_dw<<<24576, 256, 0, stream>>>(v_b, o_b, Wdw, bdw, t_b);
    k5_proj<<<1024, 256, 0, stream>>>(t_b, WTp, bp, (float*)d_out, b);
  }
}

// Round 8
// 629.892 us; speedup vs baseline: 1.3785x; 1.1311x over previous
//
#include <hip/hip_runtime.h>
#include <hip/hip_bf16.h>
#include <hip/hip_fp16.h>

#define NHEADS 3
#define SSH 4
#define NWD 32            // windows per dim
#define PXI 65536         // pixels per image plane
#define SCALE 0.17677669529663687f

typedef _Float16 f16x8 __attribute__((ext_vector_type(8)));
typedef float f32x4 __attribute__((ext_vector_type(4)));

// ---------------------------------------------------------------------------
// K0: one-time weight prep:
//   WHh fp16 [oc][96]  (A-frag layout for k1 MFMA)
//   bias288 fp32 [288] (bqk ++ bv)
//   WTp fp32 [c][oc]   (for k5 scalar-W GEMM, unchanged)
// ---------------------------------------------------------------------------
__global__ __launch_bounds__(256) void k0_wt(
    const float* __restrict__ Wqk, const float* __restrict__ Wv,
    const float* __restrict__ Wp, const float* __restrict__ bqk,
    const float* __restrict__ bv, _Float16* __restrict__ WHh,
    float* __restrict__ WTp, float* __restrict__ bias288) {
  int i = blockIdx.x * 256 + threadIdx.x;
  if (i < 288 * 96) {
    int c = i % 96, oc = i / 96;
    float w = (oc < 192) ? Wqk[oc * 96 + c] : Wv[(oc - 192) * 96 + c];
    WHh[oc * 96 + c] = (_Float16)w;
  }
  if (i < 96 * 96) {
    int c = i % 96, oc = i / 96;
    WTp[c * 96 + oc] = Wp[oc * 96 + c];
  }
  if (i < 288) bias288[i] = (i < 192) ? bqk[i] : bv[i - 192];
}

// ---------------------------------------------------------------------------
// K1: QKV 1x1 conv via MFMA. grid 1024 (64-px tiles), block 256 (4 waves).
// Wave owns 16 px x all 288 oc: 18 M-tiles x 3 k-frags.
// B (x): per-lane gather ch=32kb+8g+i at col px (same validated pattern as
//   k3's V gather), split into xh+xl fp16 (2-pass -> x-rounding error ~2^-22).
// A (W): fp16 WHh straight from global (L2-hot). Bias preloaded as C.
// No LDS, no barrier. qkv fp16 windowed + v_b fp32 plane outputs unchanged.
// ---------------------------------------------------------------------------
__global__ __launch_bounds__(256) void k1_qkv(
    const float* __restrict__ x, const _Float16* __restrict__ WHh,
    const float* __restrict__ bias288, __half* __restrict__ qkv_h,
    float* __restrict__ v_b, int b) {
  const int tid = threadIdx.x;
  const int lane = tid & 63;
  const int wv = tid >> 6;             // wave 0..3
  const int g = lane >> 4, c = lane & 15;
  const int px = blockIdx.x * 64 + wv * 16 + c;

  // ---- x gather + 2-term fp16 split
  const float* xb = x + (size_t)b * 96 * PXI + px;
  f16x8 xh[3], xl[3];
#pragma unroll
  for (int kb = 0; kb < 3; kb++) {
    float xv[8];
#pragma unroll
    for (int i = 0; i < 8; i++)
      xv[i] = xb[(size_t)(32 * kb + 8 * g + i) * PXI];
#pragma unroll
    for (int i = 0; i < 8; i++) {
      _Float16 h = (_Float16)xv[i];
      xh[kb][i] = h;
      xl[kb][i] = (_Float16)(xv[i] - (float)h);
    }
  }

  // ---- windowed-scatter indexing for this pixel
  const int hq = px >> 8, wq = px & 255;
  const int hp = (hq + 252) & 255, wp = (wq + 252) & 255;  // rolled
  const int win = (hp >> 3) * NWD + (wp >> 3);
  const int n = (hp & 7) * 8 + (wp & 7);
  __half* qdst = qkv_h + (size_t)(win * 64 + n) * 288;

  // ---- 18 M-tiles, 6 MFMA each (3 kb x {xh, xl}), C-init = bias
#pragma unroll 3
  for (int tm = 0; tm < 18; tm++) {
    f32x4 acc = *(const f32x4*)&bias288[16 * tm + 4 * g];
#pragma unroll
    for (int kb = 0; kb < 3; kb++) {
      f16x8 a = *(const f16x8*)&WHh[(size_t)(16 * tm + c) * 96 + 32 * kb + 8 * g];
      acc = __builtin_amdgcn_mfma_f32_16x16x32_f16(a, xh[kb], acc, 0, 0, 0);
      acc = __builtin_amdgcn_mfma_f32_16x16x32_f16(a, xl[kb], acc, 0, 0, 0);
    }
    // qkv fp16: 4 consecutive oc = 8 B store
    __align__(8) __half2 hv[2];
    hv[0] = __floats2half2_rn(acc[0], acc[1]);
    hv[1] = __floats2half2_rn(acc[2], acc[3]);
    *(float2*)&qdst[16 * tm + 4 * g] = *(const float2*)hv;
    // V plane fp32 (oc >= 192)
    if (tm >= 12) {
      int oc = 16 * tm + 4 * g - 192;
#pragma unroll
      for (int r = 0; r < 4; r++)
        v_b[(size_t)(oc + r) * PXI + px] = acc[r];
    }
  }
}

// ---------------------------------------------------------------------------
// K2: relative-position bias MLP -> bias_c in MFMA C-fragment layout:
// bias_c[((hd*64 + lane)*64) + (ti*4+tj)*4 + reg], where for S[n][m]:
// ti=n>>4, g=(n>>2)&3, reg=n&3, tj=m>>4, c=m&15, lane=(g<<4)|c.
// ---------------------------------------------------------------------------
__global__ __launch_bounds__(256) void k2_bias(
    const float* __restrict__ Wm1, const float* __restrict__ bm1,
    const float* __restrict__ Wm2, const float* __restrict__ bm2,
    float* __restrict__ bias_c) {
  int pair = blockIdx.x * 256 + threadIdx.x;  // 0..4095
  int n = pair >> 6, m = pair & 63;
  float d0 = (float)((n >> 3) - (m >> 3));
  float d1 = (float)((n & 7) - (m & 7));
  float r0 = (d0 > 0.f ? 1.f : (d0 < 0.f ? -1.f : 0.f)) * log1pf(fabsf(d0));
  float r1 = (d1 > 0.f ? 1.f : (d1 < 0.f ? -1.f : 0.f)) * log1pf(fabsf(d1));
  float a0 = 0.f, a1 = 0.f, a2 = 0.f;
  for (int j = 0; j < 256; j++) {
    float hb = r0 * Wm1[j] + r1 * Wm1[256 + j] + bm1[j];
    hb = fmaxf(hb, 0.f);
    a0 += hb * Wm2[j * 3 + 0];
    a1 += hb * Wm2[j * 3 + 1];
    a2 += hb * Wm2[j * 3 + 2];
  }
  int ti = n >> 4, g = (n >> 2) & 3, reg = n & 3;
  int tj = m >> 4, c = m & 15;
  int lane = (g << 4) | c;
  int idx = lane * 64 + (ti * 4 + tj) * 4 + reg;
  bias_c[0 * 4096 + idx] = a0 + bm2[0];
  bias_c[1 * 4096 + idx] = a1 + bm2[1];
  bias_c[2 * 4096 + idx] = a2 + bm2[2];
}

// ---------------------------------------------------------------------------
// K3: windowed attention via MFMA. One wave per (window, head).
// grid (1024, 3), block 64. fp16 operands, fp32 accumulate. (unchanged)
// ---------------------------------------------------------------------------
__global__ __launch_bounds__(64) void k3_attn(
    const __half* __restrict__ qkv_h, const float* __restrict__ bias_c,
    float* __restrict__ o_b) {
  __shared__ _Float16 P_lds[64 * 72];   // 9216 B
  const int lane = threadIdx.x;
  const int g = lane >> 4;             // frag k-block / C row-group
  const int c = lane & 15;             // frag row/col within tile
  const int win = blockIdx.x;
  const int hd = blockIdx.y;
  const int wh = win >> 5, ww = win & 31;

  const __half* qb = qkv_h + (size_t)win * 64 * 288 + hd * 32;

  // ---- load Q/K fragments directly from global (L2-hot)
  f16x8 qf[4], kf[4];
#pragma unroll
  for (int t = 0; t < 4; t++) {
    qf[t] = *(const f16x8*)(const void*)&qb[(size_t)(16 * t + c) * 288 + 8 * g];
    kf[t] = *(const f16x8*)(const void*)&qb[(size_t)(16 * t + c) * 288 + 96 + 8 * g];
  }
#pragma unroll
  for (int t = 0; t < 4; t++)
#pragma unroll
    for (int e = 0; e < 8; e++) qf[t][e] *= (_Float16)SCALE;

  // ---- bias preload in C layout: 16 float4 = 256B contiguous per lane
  f32x4 S[4][4];
  {
    const float* bc = bias_c + (size_t)hd * 4096 + lane * 64;
#pragma unroll
    for (int ti = 0; ti < 4; ti++)
#pragma unroll
      for (int tj = 0; tj < 4; tj++)
        S[ti][tj] = *(const f32x4*)&bc[(ti * 4 + tj) * 4];
  }

  // ---- shift-mask (uniform branch; 63/1024 windows)
  if (wh == 31 || ww == 31) {
#pragma unroll
    for (int ti = 0; ti < 4; ti++)
#pragma unroll
      for (int r = 0; r < 4; r++) {
        int row = 16 * ti + 4 * g + r;
        int rn = ((wh == 31) ? (((row >> 3) < 4) ? 1 : 2) : 0) * 3 +
                 ((ww == 31) ? (((row & 7) < 4) ? 1 : 2) : 0);
#pragma unroll
        for (int tj = 0; tj < 4; tj++) {
          int m = 16 * tj + c;
          int rm = ((wh == 31) ? (((m >> 3) < 4) ? 1 : 2) : 0) * 3 +
                   ((ww == 31) ? (((m & 7) < 4) ? 1 : 2) : 0);
          if (rm != rn) S[ti][tj][r] -= 100.f;
        }
      }
  }

  // ---- QK^T: 16 MFMA, C = bias(+mask)
#pragma unroll
  for (int tn = 0; tn < 4; tn++)
#pragma unroll
    for (int tm = 0; tm < 4; tm++)
      S[tn][tm] = __builtin_amdgcn_mfma_f32_16x16x32_f16(qf[tn], kf[tm],
                                                         S[tn][tm], 0, 0, 0);

  // ---- issue V gathers now (latency hides under softmax)
  const __half* vbse = qb + 192;
  f16x8 vf[2][2];
#pragma unroll
  for (int td = 0; td < 2; td++)
#pragma unroll
    for (int km = 0; km < 2; km++) {
      f16x8 v = {};
#pragma unroll
      for (int i = 0; i < 8; i++)
        v[i] = *(const _Float16*)&vbse[(size_t)(32 * km + 8 * g + i) * 288 +
                                       16 * td + c];
      vf[td][km] = v;
    }

  // ---- softmax (no max-subtract: S bounded by ~5; masked entries ~ -100)
#pragma unroll
  for (int ti = 0; ti < 4; ti++)
#pragma unroll
    for (int tj = 0; tj < 4; tj++)
#pragma unroll
      for (int r = 0; r < 4; r++) S[ti][tj][r] = __expf(S[ti][tj][r]);

  float invs[4][4];
#pragma unroll
  for (int ti = 0; ti < 4; ti++)
#pragma unroll
    for (int r = 0; r < 4; r++) {
      float sm = (S[ti][0][r] + S[ti][1][r]) + (S[ti][2][r] + S[ti][3][r]);
      sm += __shfl_xor(sm, 1);
      sm += __shfl_xor(sm, 2);
      sm += __shfl_xor(sm, 4);
      sm += __shfl_xor(sm, 8);
      invs[ti][r] = 1.f / sm;
    }

  // ---- P -> fp16 LDS [row][72h], col XOR 8 when row&8 (bank de-alias)
  {
#pragma unroll
    for (int ti = 0; ti < 4; ti++)
#pragma unroll
      for (int r = 0; r < 4; r++) {
        int row = 16 * ti + 4 * g + r;
        int rx = (4 * g + r) & 8;      // == row&8
#pragma unroll
        for (int tj = 0; tj < 4; tj++)
          P_lds[row * 72 + ((16 * tj + c) ^ rx)] = (_Float16)S[ti][tj][r];
      }
  }

  // ---- PV: O[64][32] = P.V as 4x2 tiles, K=64 (2 chained MFMA)
  f32x4 O[4][2];
#pragma unroll
  for (int tn = 0; tn < 4; tn++) {
    const int row = 16 * tn + c;
    const int rx = c & 8;
    f16x8 pf0 = *(const f16x8*)(const void*)&P_lds[row * 72 + ((8 * g) ^ rx)];
    f16x8 pf1 = *(const f16x8*)(const void*)&P_lds[row * 72 + ((32 + 8 * g) ^ rx)];
#pragma unroll
    for (int td = 0; td < 2; td++) {
      f32x4 oo = {0.f, 0.f, 0.f, 0.f};
      oo = __builtin_amdgcn_mfma_f32_16x16x32_f16(pf0, vf[td][0], oo, 0, 0, 0);
      oo = __builtin_amdgcn_mfma_f32_16x16x32_f16(pf1, vf[td][1], oo, 0, 0, 0);
      O[tn][td] = oo;
    }
  }

  // ---- store (normalize by row sum here)
#pragma unroll
  for (int tn = 0; tn < 4; tn++)
#pragma unroll
    for (int r = 0; r < 4; r++) {
      int row = 16 * tn + 4 * g + r;
      int hpix = ((wh << 3) + (row >> 3) + SSH) & 255;
      int wpix = ((ww << 3) + (row & 7) + SSH) & 255;
      size_t pix = (size_t)(hpix << 8) + wpix;
      float inv = invs[tn][r];
#pragma unroll
      for (int td = 0; td < 2; td++) {
        int cch = hd * 32 + 16 * td + c;
        o_b[(size_t)cch * PXI + pix] = O[tn][td][r] * inv;
      }
    }
}

// ---------------------------------------------------------------------------
// K4: depthwise 5x5 (reflect pad) + bdw + O -> t_b, per image. grid 24576.
// ---------------------------------------------------------------------------
__global__ __launch_bounds__(256) void k4_dw(
    const float* __restrict__ v_b, const float* __restrict__ o_b,
    const float* __restrict__ Wdw, const float* __restrict__ bdw,
    float* __restrict__ t_b) {
  const int blk = blockIdx.x;      // 0..24575
  const int c = blk >> 8;
  const int h = blk & 255;
  const int w = threadIdx.x;
  __shared__ float wd[25];
  __shared__ float bd;
  if (threadIdx.x < 25) wd[threadIdx.x] = Wdw[c * 25 + threadIdx.x];
  if (threadIdx.x == 32) bd = bdw[c];
  __syncthreads();

  const float* vp = v_b + ((size_t)c << 16);
  float acc = bd;
#pragma unroll
  for (int dy = 0; dy < 5; dy++) {
    int hh = h + dy - 2;
    hh = hh < 0 ? -hh : (hh > 255 ? 510 - hh : hh);
    const float* row = vp + (hh << 8);
#pragma unroll
    for (int dx = 0; dx < 5; dx++) {
      int wx = w + dx - 2;
      wx = wx < 0 ? -wx : (wx > 255 ? 510 - wx : wx);
      acc += row[wx] * wd[dy * 5 + dx];
    }
  }
  size_t idx = ((size_t)c << 16) + (h << 8) + w;
  acc += o_b[idx];
  t_b[idx] = acc;
}

// ---------------------------------------------------------------------------
// K5: projection GEMM 96x96 for image b -> d_out (fp32 NCHW).
// 64-px tiles, 24KB LDS, 6 blocks/CU. grid 1024. (unchanged)
// ---------------------------------------------------------------------------
__global__ __launch_bounds__(256) void k5_proj(
    const float* __restrict__ t_b, const float* __restrict__ WTp,
    const float* __restrict__ bp, float* __restrict__ out, int b) {
  __shared__ __align__(16) float Xt[96 * 64];
  const int tid = threadIdx.x;
  const int pt = blockIdx.x;
  const int p0 = pt * 64;

  for (int i = tid; i < 96 * 16; i += 256) {
    int c = i >> 4, f = i & 15;
    *(float4*)&Xt[c * 64 + f * 4] =
        *(const float4*)&t_b[(size_t)c * PXI + p0 + f * 4];
  }
  __syncthreads();

  const int lane = tid & 63;
  const int wvu = __builtin_amdgcn_readfirstlane(tid >> 6);
  const int oc0 = wvu * 24;

  float acc[24];
#pragma unroll
  for (int r = 0; r < 24; r++) acc[r] = 0.f;

  const float* wt = WTp + oc0;
#pragma unroll 4
  for (int c = 0; c < 96; c++) {
    float xa = Xt[c * 64 + lane];
    const float* wc = wt + c * 96;      // uniform -> s_load
#pragma unroll
    for (int r = 0; r < 24; r++) acc[r] += wc[r] * xa;
  }

  int p = p0 + lane;
#pragma unroll
  for (int r = 0; r < 24; r++) {
    int oc = oc0 + r;
    out[(size_t)(b * 96 + oc) * PXI + p] = acc[r] + bp[oc];
  }
}

// ---------------------------------------------------------------------------
extern "C" void kernel_launch(void* const* d_in, const int* in_sizes, int n_in,
                              void* d_out, int out_size, void* d_ws,
                              size_t ws_size, hipStream_t stream) {
  const float* x   = (const float*)d_in[0];
  const float* Wv  = (const float*)d_in[1];
  const float* bv  = (const float*)d_in[2];
  const float* Wqk = (const float*)d_in[3];
  const float* bqk = (const float*)d_in[4];
  const float* Wm1 = (const float*)d_in[5];
  const float* bm1 = (const float*)d_in[6];
  const float* Wm2 = (const float*)d_in[7];
  const float* bm2 = (const float*)d_in[8];
  const float* Wdw = (const float*)d_in[9];
  const float* bdw = (const float*)d_in[10];
  const float* Wp  = (const float*)d_in[11];
  const float* bp  = (const float*)d_in[12];

  // per-image workspace (reused across b):
  //   [0, 37748736)            qkv_h  fp16 [1024][64][288]  (t_b aliases)
  //   [37748736, 62914560)     v_b    fp32 [96][65536]
  //   [62914560, 88080384)     o_b    fp32 [96][65536]
  //   [88080384, 88129536)     bias_c fp32 [3][64][64] (C-frag layout)
  //   [88129536, 88166400)     WTp fp32 [96][96]
  //   [88166400, 88221696)     WHh fp16 [288][96] (A-frag layout)
  //   [88221696, 88222848)     bias288 fp32 [288]
  char* ws = (char*)d_ws;
  __half* qkv_h = (__half*)ws;
  float* t_b   = (float*)ws;           // 25 MB, alias of dead qkv region
  float* v_b   = (float*)(ws + 37748736);
  float* o_b   = (float*)(ws + 62914560);
  float* bias_c = (float*)(ws + 88080384);
  float* WTp   = (float*)(ws + 88129536);
  _Float16* WHh = (_Float16*)(ws + 88166400);
  float* bias288 = (float*)(ws + 88221696);

  k0_wt<<<108, 256, 0, stream>>>(Wqk, Wv, Wp, bqk, bv, WHh, WTp, bias288);
  k2_bias<<<16, 256, 0, stream>>>(Wm1, bm1, Wm2, bm2, bias_c);
  for (int b = 0; b < 4; b++) {
    k1_qkv<<<1024, 256, 0, stream>>>(x, WHh, bias288, qkv_h, v_b, b);
    k3_attn<<<dim3(1024, 3), 64, 0, stream>>>(qkv_h, bias_c, o_b);
    k4_dw<<<24576, 256, 0, stream>>>(v_b, o_b, Wdw, bdw, t_b);
    k5_proj<<<1024, 256, 0, stream>>>(t_b, WTp, bp, (float*)d_out, b);
  }
}